// Round 4
// baseline (382.565 us; speedup 1.0000x reference)
//
#include <hip/hip_runtime.h>
#include <hip/hip_bf16.h>
#include <cstdint>
#include <cstddef>

#define NROWS 8192
#define MCOLS 8192
#define DDIM  512
#define GRP   10

using f32x4 = __attribute__((ext_vector_type(4))) float;
using i32x8 = __attribute__((ext_vector_type(8))) int;

typedef const __attribute__((address_space(1))) void* gas_ptr;
typedef __attribute__((address_space(3))) void* las_ptr;

// ---------------------------------------------------------------------------
// Kernel 1: cast fp32 rows -> fp8 e4m3 + per-row sum of squares (fp32-exact).
// Block 2*NROWS computes the 10x10 group tables, packed (t, c2) as float2:
//   val(a,b) = 1 / (|gdp| * ||e_a - e_b||^2 + 1)
//   t  = -0.5 * val / ls^2       (exp argument multiplier)
//   c2 = sigma^2 * val^256       (prefactor)
// ---------------------------------------------------------------------------
__global__ __launch_bounds__(256) void prep_all(const float* __restrict__ X,
                                                const float* __restrict__ Z,
                                                uint16_t* __restrict__ Xa,
                                                uint16_t* __restrict__ Za,
                                                float* __restrict__ xx,
                                                float* __restrict__ zz,
                                                const float* __restrict__ emb,
                                                const float* __restrict__ sigma_p,
                                                const float* __restrict__ ls_p,
                                                const float* __restrict__ gdp_p,
                                                float2* __restrict__ tab) {
    int row = blockIdx.x;
    int t = threadIdx.x;
    if (row == 2 * NROWS) {            // table block
        if (t >= GRP * GRP) return;
        int a = t / GRP, b = t % GRP;
        float gd = 0.0f;
        #pragma unroll
        for (int g = 0; g < GRP; ++g) {
            float d = emb[a * GRP + g] - emb[b * GRP + g];
            gd += d * d;
        }
        float val = 1.0f / (fabsf(*gdp_p) * gd + 1.0f);
        float ls = *ls_p;
        float sg = *sigma_p;
        tab[t] = make_float2(-0.5f * val / (ls * ls),
                             sg * sg * powf(val, 0.5f * (float)DDIM));
        return;
    }
    const float* src;
    uint16_t* dst;
    float* sums;
    int r;
    if (row < NROWS) {
        r = row; src = X + (size_t)r * DDIM; dst = Xa + (size_t)r * (DDIM / 2); sums = xx;
    } else {
        r = row - NROWS; src = Z + (size_t)r * DDIM; dst = Za + (size_t)r * (DDIM / 2); sums = zz;
    }
    float2 p = ((const float2*)src)[t];          // 8B/lane coalesced
    // pack 2x fp8 e4m3 (OCP). Consistent k-order for A and B, so any
    // k-permutation cancels in the dot product.
    int packed = __builtin_amdgcn_cvt_pk_fp8_f32(p.x, p.y, 0, false);
    dst[t] = (uint16_t)packed;                   // 2B/lane coalesced
    float s = p.x * p.x + p.y * p.y;
    #pragma unroll
    for (int off = 32; off > 0; off >>= 1) s += __shfl_down(s, off, 64);
    __shared__ float ws[4];
    if ((t & 63) == 0) ws[t >> 6] = s;
    __syncthreads();
    if (t == 0) sums[r] = ws[0] + ws[1] + ws[2] + ws[3];
}

// ---------------------------------------------------------------------------
// Kernel 2: MX-scaled fp8 MFMA GEMM (X @ Z^T) + fused MGGP-RBF epilogue.
// 128x128 tile, BK=128 (4 K-iters), 4 waves, each wave 64x64 as 4x4 of
// 16x16x128 f8f6f4 MFMA (fmt=0 -> fp8 e4m3) with all E8M0 scales = 127
// (scale 1.0): plain fp8 GEMM at 2x the non-scaled rate, 4x fewer MFMAs.
// Fragment = 32 B/lane (v8i32), k = q*32..q*32+31 for lane quad q; identical
// A/B lane maps make any internal k-order cancel in the dot product.
// LDS row = 128 B. Swizzle at 32B-granule level: physical granule
// PG = G ^ (r&3)  (G = logical granule 0..3). 32B fragment reads then spread
// uniformly over all 32 banks; staging keeps 16B chunks pair-contiguous:
// logical chunk c = pc ^ ((r&3)<<1).
// ---------------------------------------------------------------------------
__global__ __launch_bounds__(256) void mggp_gemm(
    const uint8_t* __restrict__ Xa, const uint8_t* __restrict__ Za,
    const float* __restrict__ xx, const float* __restrict__ zz,
    const int* __restrict__ gX, const int* __restrict__ gZ,
    const float2* __restrict__ tab,
    float* __restrict__ out) {

    __shared__ __align__(32) uint8_t Al[128 * 128];   // 16 KB
    __shared__ __align__(32) uint8_t Bl[128 * 128];   // 16 KB

    const int tid  = threadIdx.x;
    const int lane = tid & 63;
    const int w    = tid >> 6;       // wave 0..3
    const int wr   = w >> 1;         // wave row (0..1)
    const int wc   = w & 1;          // wave col (0..1)
    const int m    = lane & 15;      // row/col within 16-tile
    const int q    = lane >> 4;      // k-block quad (0..3), 32 fp8 each

    // 8x8 supertile remap (consecutive ids round-robin XCDs)
    const int lin = blockIdx.x;
    const int st  = lin >> 6;
    const int wi  = lin & 63;
    const int bx  = (st & 7) * 8 + (wi & 7);
    const int by  = (st >> 3) * 8 + (wi >> 3);
    const int brow = by * 128;
    const int bcol = bx * 128;

    f32x4 acc[4][4];
    #pragma unroll
    for (int ti = 0; ti < 4; ++ti)
        #pragma unroll
        for (int tj = 0; tj < 4; ++tj)
            #pragma unroll
            for (int e = 0; e < 4; ++e) acc[ti][tj][e] = 0.0f;

    for (int kt = 0; kt < DDIM / 128; ++kt) {
        __syncthreads();   // previous iter's LDS reads done before overwrite
        #pragma unroll
        for (int p = 0; p < 4; ++p) {
            int sbase = (w * 4 + p) * 64;       // slot = 16 B; 1024 slots/matrix
            int s = sbase + lane;
            int r = s >> 3;                     // tile row 0..127
            int pc = s & 7;                     // physical 16B chunk in row
            int c = pc ^ ((r & 3) << 1);        // logical (global) chunk
            const uint8_t* ga = Xa + (size_t)(brow + r) * DDIM + kt * 128 + c * 16;
            __builtin_amdgcn_global_load_lds((gas_ptr)ga, (las_ptr)&Al[sbase * 16], 16, 0, 0);
            const uint8_t* gb = Za + (size_t)(bcol + r) * DDIM + kt * 128 + c * 16;
            __builtin_amdgcn_global_load_lds((gas_ptr)gb, (las_ptr)&Bl[sbase * 16], 16, 0, 0);
        }
        __syncthreads();   // vmcnt(0) drain before s_barrier

        i32x8 aF[4], bF[4];
        #pragma unroll
        for (int ti = 0; ti < 4; ++ti) {
            int r = wr * 64 + ti * 16 + m;
            int pg = q ^ (r & 3);               // physical 32B granule
            aF[ti] = *(const i32x8*)&Al[r * 128 + pg * 32];
        }
        #pragma unroll
        for (int tj = 0; tj < 4; ++tj) {
            int r = wc * 64 + tj * 16 + m;
            int pg = q ^ (r & 3);
            bF[tj] = *(const i32x8*)&Bl[r * 128 + pg * 32];
        }
        #pragma unroll
        for (int ti = 0; ti < 4; ++ti)
            #pragma unroll
            for (int tj = 0; tj < 4; ++tj)
                acc[ti][tj] = __builtin_amdgcn_mfma_scale_f32_16x16x128_f8f6f4(
                    aF[ti], bF[tj], acc[ti][tj],
                    0, 0,                    // cbsz=fp8(e4m3), blgp=fp8(e4m3)
                    0, 0x7f7f7f7f,           // scale A: E8M0 127 -> 1.0
                    0, 0x7f7f7f7f);          // scale B: E8M0 127 -> 1.0
    }

    // ---- epilogue: K = c2[ga][gb] * exp(dist * t[ga][gb]) ----
    float zzv[4];
    int   gbv[4];
    #pragma unroll
    for (int tj = 0; tj < 4; ++tj) {
        int j = bcol + wc * 64 + tj * 16 + m;   // lane's column (C/D: col=lane&15)
        zzv[tj] = zz[j];
        gbv[tj] = gZ[j];
    }
    #pragma unroll
    for (int ti = 0; ti < 4; ++ti) {
        #pragma unroll
        for (int rg = 0; rg < 4; ++rg) {
            int i = brow + wr * 64 + ti * 16 + q * 4 + rg;  // C/D: row=quad*4+reg
            float xxi = xx[i];
            int   ga  = gX[i] * GRP;
            float* orow = out + (size_t)i * MCOLS + bcol + wc * 64 + m;
            #pragma unroll
            for (int tj = 0; tj < 4; ++tj) {
                float dot  = acc[ti][tj][rg];
                float dist = xxi + zzv[tj] - 2.0f * dot;
                float2 tc  = tab[ga + gbv[tj]];
                orow[tj * 16] = tc.y * __expf(dist * tc.x);
            }
        }
    }
}

// ---------------------------------------------------------------------------
extern "C" void kernel_launch(void* const* d_in, const int* in_sizes, int n_in,
                              void* d_out, int out_size, void* d_ws, size_t ws_size,
                              hipStream_t stream) {
    const float* X     = (const float*)d_in[0];
    const float* Z     = (const float*)d_in[1];
    const int*   gX    = (const int*)d_in[2];
    const int*   gZ    = (const int*)d_in[3];
    const float* emb   = (const float*)d_in[4];
    const float* sigma = (const float*)d_in[5];
    const float* ls    = (const float*)d_in[6];
    const float* gdp   = (const float*)d_in[7];

    char* ws = (char*)d_ws;
    const size_t XA_OFF  = 0;                              // 8192*512 = 4 MiB
    const size_t ZA_OFF  = XA_OFF + (size_t)NROWS * DDIM;  // 4 MiB
    const size_t XX_OFF  = ZA_OFF + (size_t)MCOLS * DDIM;
    const size_t ZZ_OFF  = XX_OFF + (size_t)NROWS * 4;
    const size_t TAB_OFF = ZZ_OFF + (size_t)MCOLS * 4;

    uint8_t* Xa  = (uint8_t*)(ws + XA_OFF);
    uint8_t* Za  = (uint8_t*)(ws + ZA_OFF);
    float* xx    = (float*)(ws + XX_OFF);
    float* zz    = (float*)(ws + ZZ_OFF);
    float2* tab  = (float2*)(ws + TAB_OFF);

    prep_all<<<2 * NROWS + 1, 256, 0, stream>>>(X, Z, (uint16_t*)Xa, (uint16_t*)Za,
                                                xx, zz, emb, sigma, ls, gdp, tab);
    mggp_gemm<<<4096, 256, 0, stream>>>(Xa, Za, xx, zz, gX, gZ, tab, (float*)d_out);
}

// Round 5
// 337.275 us; speedup vs baseline: 1.1343x; 1.1343x over previous
//
#include <hip/hip_runtime.h>
#include <hip/hip_bf16.h>
#include <cstdint>
#include <cstddef>

#define NROWS 8192
#define MCOLS 8192
#define DDIM  512
#define GRP   10

using f32x4 = __attribute__((ext_vector_type(4))) float;

typedef const __attribute__((address_space(1))) void* gas_ptr;
typedef __attribute__((address_space(3))) void* las_ptr;

// ---------------------------------------------------------------------------
// Kernel 1: cast fp32 rows -> fp8 e4m3 + per-row sum of squares (fp32-exact).
// Block 2*NROWS computes the 10x10 group tables, packed (t, c2) as float2:
//   val(a,b) = 1 / (|gdp| * ||e_a - e_b||^2 + 1)
//   t  = -0.5 * val / ls^2       (exp argument multiplier)
//   c2 = sigma^2 * val^256       (prefactor)
// ---------------------------------------------------------------------------
__global__ __launch_bounds__(256) void prep_all(const float* __restrict__ X,
                                                const float* __restrict__ Z,
                                                uint16_t* __restrict__ Xa,
                                                uint16_t* __restrict__ Za,
                                                float* __restrict__ xx,
                                                float* __restrict__ zz,
                                                const float* __restrict__ emb,
                                                const float* __restrict__ sigma_p,
                                                const float* __restrict__ ls_p,
                                                const float* __restrict__ gdp_p,
                                                float2* __restrict__ tab) {
    int row = blockIdx.x;
    int t = threadIdx.x;
    if (row == 2 * NROWS) {            // table block
        if (t >= GRP * GRP) return;
        int a = t / GRP, b = t % GRP;
        float gd = 0.0f;
        #pragma unroll
        for (int g = 0; g < GRP; ++g) {
            float d = emb[a * GRP + g] - emb[b * GRP + g];
            gd += d * d;
        }
        float val = 1.0f / (fabsf(*gdp_p) * gd + 1.0f);
        float ls = *ls_p;
        float sg = *sigma_p;
        tab[t] = make_float2(-0.5f * val / (ls * ls),
                             sg * sg * powf(val, 0.5f * (float)DDIM));
        return;
    }
    const float* src;
    uint16_t* dst;
    float* sums;
    int r;
    if (row < NROWS) {
        r = row; src = X + (size_t)r * DDIM; dst = Xa + (size_t)r * (DDIM / 2); sums = xx;
    } else {
        r = row - NROWS; src = Z + (size_t)r * DDIM; dst = Za + (size_t)r * (DDIM / 2); sums = zz;
    }
    float2 p = ((const float2*)src)[t];          // 8B/lane coalesced
    // pack 2x fp8 e4m3 (OCP). Consistent k-order for A and B, so any
    // k-permutation cancels in the dot product.
    int packed = __builtin_amdgcn_cvt_pk_fp8_f32(p.x, p.y, 0, false);
    dst[t] = (uint16_t)packed;                   // 2B/lane coalesced
    float s = p.x * p.x + p.y * p.y;
    #pragma unroll
    for (int off = 32; off > 0; off >>= 1) s += __shfl_down(s, off, 64);
    __shared__ float ws[4];
    if ((t & 63) == 0) ws[t >> 6] = s;
    __syncthreads();
    if (t == 0) sums[r] = ws[0] + ws[1] + ws[2] + ws[3];
}

// ---------------------------------------------------------------------------
// Kernel 2: fp8 MFMA GEMM (X @ Z^T) + fused MGGP-RBF epilogue.
// 128x128 tile, BK=128 (4 K-iters), 4 waves, each wave 64x64 as 4x4 of
// 16x16x32 fp8_fp8 MFMA. Reverted from the R4 MX-scaled variant: its
// 64-VGPR i32x8 fragments dropped occupancy 3->2 blocks/CU and cost +14 us
// by un-hiding the barrier drains + epilogue write tail.
// __launch_bounds__(256,3): guarantee >=3 waves/EU (VGPR cap 170 >> ~130
// needed -> no spill risk), protecting the 3-block/CU overlap regime.
// LDS row = 128 B. XOR swizzle on the GLOBAL source (LDS dest must be
// wave-uniform base + lane*16): physical 16B chunk pc = c ^ (r&7)
// <=> physical 8B granule pg = g ^ (2*(r&7)); fragment ds_read_b64 lands
// 2-way max on banks = free per m136.
// ---------------------------------------------------------------------------
__global__ __launch_bounds__(256, 3) void mggp_gemm(
    const uint8_t* __restrict__ Xa, const uint8_t* __restrict__ Za,
    const float* __restrict__ xx, const float* __restrict__ zz,
    const int* __restrict__ gX, const int* __restrict__ gZ,
    const float2* __restrict__ tab,
    float* __restrict__ out) {

    __shared__ __align__(16) uint8_t Al[128 * 128];   // 16 KB
    __shared__ __align__(16) uint8_t Bl[128 * 128];   // 16 KB

    const int tid  = threadIdx.x;
    const int lane = tid & 63;
    const int w    = tid >> 6;       // wave 0..3
    const int wr   = w >> 1;         // wave row (0..1)
    const int wc   = w & 1;          // wave col (0..1)
    const int m    = lane & 15;      // row/col within 16-tile
    const int q    = lane >> 4;      // k-octet quad (0..3)

    // 8x8 supertile remap (consecutive ids round-robin XCDs)
    const int lin = blockIdx.x;
    const int st  = lin >> 6;
    const int wi  = lin & 63;
    const int bx  = (st & 7) * 8 + (wi & 7);
    const int by  = (st >> 3) * 8 + (wi >> 3);
    const int brow = by * 128;
    const int bcol = bx * 128;

    f32x4 acc[4][4];
    #pragma unroll
    for (int ti = 0; ti < 4; ++ti)
        #pragma unroll
        for (int tj = 0; tj < 4; ++tj)
            #pragma unroll
            for (int e = 0; e < 4; ++e) acc[ti][tj][e] = 0.0f;

    for (int kt = 0; kt < DDIM / 128; ++kt) {
        __syncthreads();   // previous iter's LDS reads done before overwrite
        #pragma unroll
        for (int p = 0; p < 4; ++p) {
            int sbase = (w * 4 + p) * 64;       // slot = 16 B; 1024 slots/matrix
            int s = sbase + lane;
            int r = s >> 3;                     // tile row 0..127
            int c = (s & 7) ^ (r & 7);          // global 16B chunk within row
            const uint8_t* ga = Xa + (size_t)(brow + r) * DDIM + kt * 128 + c * 16;
            __builtin_amdgcn_global_load_lds((gas_ptr)ga, (las_ptr)&Al[sbase * 16], 16, 0, 0);
            const uint8_t* gb = Za + (size_t)(bcol + r) * DDIM + kt * 128 + c * 16;
            __builtin_amdgcn_global_load_lds((gas_ptr)gb, (las_ptr)&Bl[sbase * 16], 16, 0, 0);
        }
        __syncthreads();   // vmcnt(0) drain before s_barrier

        #pragma unroll
        for (int kk = 0; kk < 4; ++kk) {
            long aF[4], bF[4];
            #pragma unroll
            for (int ti = 0; ti < 4; ++ti) {
                int r = wr * 64 + ti * 16 + m;
                int pg = (kk * 4 + q) ^ ((r & 7) << 1);   // physical 8B granule
                aF[ti] = *(const long*)&Al[r * 128 + pg * 8];
            }
            #pragma unroll
            for (int tj = 0; tj < 4; ++tj) {
                int r = wc * 64 + tj * 16 + m;
                int pg = (kk * 4 + q) ^ ((r & 7) << 1);
                bF[tj] = *(const long*)&Bl[r * 128 + pg * 8];
            }
            #pragma unroll
            for (int ti = 0; ti < 4; ++ti)
                #pragma unroll
                for (int tj = 0; tj < 4; ++tj)
                    acc[ti][tj] = __builtin_amdgcn_mfma_f32_16x16x32_fp8_fp8(
                        aF[ti], bF[tj], acc[ti][tj], 0, 0, 0);
        }
    }

    // ---- epilogue: K = c2[ga][gb] * exp(dist * t[ga][gb]) ----
    float zzv[4];
    int   gbv[4];
    #pragma unroll
    for (int tj = 0; tj < 4; ++tj) {
        int j = bcol + wc * 64 + tj * 16 + m;   // lane's column (C/D: col=lane&15)
        zzv[tj] = zz[j];
        gbv[tj] = gZ[j];
    }
    #pragma unroll
    for (int ti = 0; ti < 4; ++ti) {
        #pragma unroll
        for (int rg = 0; rg < 4; ++rg) {
            int i = brow + wr * 64 + ti * 16 + q * 4 + rg;  // C/D: row=quad*4+reg
            float xxi = xx[i];
            int   ga  = gX[i] * GRP;
            float* orow = out + (size_t)i * MCOLS + bcol + wc * 64 + m;
            #pragma unroll
            for (int tj = 0; tj < 4; ++tj) {
                float dot  = acc[ti][tj][rg];
                float dist = xxi + zzv[tj] - 2.0f * dot;
                float2 tc  = tab[ga + gbv[tj]];
                orow[tj * 16] = tc.y * __expf(dist * tc.x);
            }
        }
    }
}

// ---------------------------------------------------------------------------
extern "C" void kernel_launch(void* const* d_in, const int* in_sizes, int n_in,
                              void* d_out, int out_size, void* d_ws, size_t ws_size,
                              hipStream_t stream) {
    const float* X     = (const float*)d_in[0];
    const float* Z     = (const float*)d_in[1];
    const int*   gX    = (const int*)d_in[2];
    const int*   gZ    = (const int*)d_in[3];
    const float* emb   = (const float*)d_in[4];
    const float* sigma = (const float*)d_in[5];
    const float* ls    = (const float*)d_in[6];
    const float* gdp   = (const float*)d_in[7];

    char* ws = (char*)d_ws;
    const size_t XA_OFF  = 0;                              // 8192*512 = 4 MiB
    const size_t ZA_OFF  = XA_OFF + (size_t)NROWS * DDIM;  // 4 MiB
    const size_t XX_OFF  = ZA_OFF + (size_t)MCOLS * DDIM;
    const size_t ZZ_OFF  = XX_OFF + (size_t)NROWS * 4;
    const size_t TAB_OFF = ZZ_OFF + (size_t)MCOLS * 4;

    uint8_t* Xa  = (uint8_t*)(ws + XA_OFF);
    uint8_t* Za  = (uint8_t*)(ws + ZA_OFF);
    float* xx    = (float*)(ws + XX_OFF);
    float* zz    = (float*)(ws + ZZ_OFF);
    float2* tab  = (float2*)(ws + TAB_OFF);

    prep_all<<<2 * NROWS + 1, 256, 0, stream>>>(X, Z, (uint16_t*)Xa, (uint16_t*)Za,
                                                xx, zz, emb, sigma, ls, gdp, tab);
    mggp_gemm<<<4096, 256, 0, stream>>>(Xa, Za, xx, zz, gX, gZ, tab, (float*)d_out);
}

// Round 6
// 336.354 us; speedup vs baseline: 1.1374x; 1.0027x over previous
//
#include <hip/hip_runtime.h>
#include <hip/hip_bf16.h>
#include <cstdint>
#include <cstddef>

#define NROWS 8192
#define MCOLS 8192
#define DDIM  512
#define GRP   10

using f32x4 = __attribute__((ext_vector_type(4))) float;

typedef const __attribute__((address_space(1))) void* gas_ptr;
typedef __attribute__((address_space(3))) void* las_ptr;

// ---------------------------------------------------------------------------
// Kernel 1: cast fp32 rows -> fp8 e4m3 + per-row sum of squares (fp32-exact).
// Block 2*NROWS computes the 10x10 group tables, packed (t, c2) as float2:
//   val(a,b) = 1 / (|gdp| * ||e_a - e_b||^2 + 1)
//   t  = -0.5 * val / ls^2       (exp argument multiplier)
//   c2 = sigma^2 * val^256       (prefactor)
// ---------------------------------------------------------------------------
__global__ __launch_bounds__(256) void prep_all(const float* __restrict__ X,
                                                const float* __restrict__ Z,
                                                uint16_t* __restrict__ Xa,
                                                uint16_t* __restrict__ Za,
                                                float* __restrict__ xx,
                                                float* __restrict__ zz,
                                                const float* __restrict__ emb,
                                                const float* __restrict__ sigma_p,
                                                const float* __restrict__ ls_p,
                                                const float* __restrict__ gdp_p,
                                                float2* __restrict__ tab) {
    int row = blockIdx.x;
    int t = threadIdx.x;
    if (row == 2 * NROWS) {            // table block
        if (t >= GRP * GRP) return;
        int a = t / GRP, b = t % GRP;
        float gd = 0.0f;
        #pragma unroll
        for (int g = 0; g < GRP; ++g) {
            float d = emb[a * GRP + g] - emb[b * GRP + g];
            gd += d * d;
        }
        float val = 1.0f / (fabsf(*gdp_p) * gd + 1.0f);
        float ls = *ls_p;
        float sg = *sigma_p;
        tab[t] = make_float2(-0.5f * val / (ls * ls),
                             sg * sg * powf(val, 0.5f * (float)DDIM));
        return;
    }
    const float* src;
    uint16_t* dst;
    float* sums;
    int r;
    if (row < NROWS) {
        r = row; src = X + (size_t)r * DDIM; dst = Xa + (size_t)r * (DDIM / 2); sums = xx;
    } else {
        r = row - NROWS; src = Z + (size_t)r * DDIM; dst = Za + (size_t)r * (DDIM / 2); sums = zz;
    }
    float2 p = ((const float2*)src)[t];          // 8B/lane coalesced
    // pack 2x fp8 e4m3 (OCP). Consistent k-order for A and B, so any
    // k-permutation cancels in the dot product.
    int packed = __builtin_amdgcn_cvt_pk_fp8_f32(p.x, p.y, 0, false);
    dst[t] = (uint16_t)packed;                   // 2B/lane coalesced
    float s = p.x * p.x + p.y * p.y;
    #pragma unroll
    for (int off = 32; off > 0; off >>= 1) s += __shfl_down(s, off, 64);
    __shared__ float ws[4];
    if ((t & 63) == 0) ws[t >> 6] = s;
    __syncthreads();
    if (t == 0) sums[r] = ws[0] + ws[1] + ws[2] + ws[3];
}

// ---------------------------------------------------------------------------
// Kernel 2: fp8 MFMA GEMM (X @ Z^T) + fused MGGP-RBF epilogue.
// 128x128 tile, BK=128 (4 K-iters), 4 waves, each wave 64x64 as 4x4 of
// 16x16x32 fp8_fp8 MFMA.
// OCCUPANCY IS THE LEVER (R4/R5 evidence): unbounded allocator used >170
// VGPRs -> 2 blocks/CU; (256,3) forced <=170 -> 3 blocks/CU, -31 us.
// This round: (256,4) -> VGPR cap 128, 4 blocks/CU (LDS 4x32KB=128<=160KB).
// Live state acc 64 + frags 16 + addressing ~ fits; watch for scratch spill.
// LDS row = 128 B. XOR swizzle on the GLOBAL source (LDS dest must be
// wave-uniform base + lane*16): physical 16B chunk pc = c ^ (r&7)
// <=> physical 8B granule pg = g ^ (2*(r&7)); fragment ds_read_b64 lands
// 2-way max on banks = free per m136.
// ---------------------------------------------------------------------------
__global__ __launch_bounds__(256, 4) void mggp_gemm(
    const uint8_t* __restrict__ Xa, const uint8_t* __restrict__ Za,
    const float* __restrict__ xx, const float* __restrict__ zz,
    const int* __restrict__ gX, const int* __restrict__ gZ,
    const float2* __restrict__ tab,
    float* __restrict__ out) {

    __shared__ __align__(16) uint8_t Al[128 * 128];   // 16 KB
    __shared__ __align__(16) uint8_t Bl[128 * 128];   // 16 KB

    const int tid  = threadIdx.x;
    const int lane = tid & 63;
    const int w    = tid >> 6;       // wave 0..3
    const int wr   = w >> 1;         // wave row (0..1)
    const int wc   = w & 1;          // wave col (0..1)
    const int m    = lane & 15;      // row/col within 16-tile
    const int q    = lane >> 4;      // k-octet quad (0..3)

    // 8x8 supertile remap (consecutive ids round-robin XCDs)
    const int lin = blockIdx.x;
    const int st  = lin >> 6;
    const int wi  = lin & 63;
    const int bx  = (st & 7) * 8 + (wi & 7);
    const int by  = (st >> 3) * 8 + (wi >> 3);
    const int brow = by * 128;
    const int bcol = bx * 128;

    f32x4 acc[4][4];
    #pragma unroll
    for (int ti = 0; ti < 4; ++ti)
        #pragma unroll
        for (int tj = 0; tj < 4; ++tj)
            #pragma unroll
            for (int e = 0; e < 4; ++e) acc[ti][tj][e] = 0.0f;

    for (int kt = 0; kt < DDIM / 128; ++kt) {
        __syncthreads();   // previous iter's LDS reads done before overwrite
        #pragma unroll
        for (int p = 0; p < 4; ++p) {
            int sbase = (w * 4 + p) * 64;       // slot = 16 B; 1024 slots/matrix
            int s = sbase + lane;
            int r = s >> 3;                     // tile row 0..127
            int c = (s & 7) ^ (r & 7);          // global 16B chunk within row
            const uint8_t* ga = Xa + (size_t)(brow + r) * DDIM + kt * 128 + c * 16;
            __builtin_amdgcn_global_load_lds((gas_ptr)ga, (las_ptr)&Al[sbase * 16], 16, 0, 0);
            const uint8_t* gb = Za + (size_t)(bcol + r) * DDIM + kt * 128 + c * 16;
            __builtin_amdgcn_global_load_lds((gas_ptr)gb, (las_ptr)&Bl[sbase * 16], 16, 0, 0);
        }
        __syncthreads();   // vmcnt(0) drain before s_barrier

        #pragma unroll
        for (int kk = 0; kk < 4; ++kk) {
            long aF[4], bF[4];
            #pragma unroll
            for (int ti = 0; ti < 4; ++ti) {
                int r = wr * 64 + ti * 16 + m;
                int pg = (kk * 4 + q) ^ ((r & 7) << 1);   // physical 8B granule
                aF[ti] = *(const long*)&Al[r * 128 + pg * 8];
            }
            #pragma unroll
            for (int tj = 0; tj < 4; ++tj) {
                int r = wc * 64 + tj * 16 + m;
                int pg = (kk * 4 + q) ^ ((r & 7) << 1);
                bF[tj] = *(const long*)&Bl[r * 128 + pg * 8];
            }
            #pragma unroll
            for (int ti = 0; ti < 4; ++ti)
                #pragma unroll
                for (int tj = 0; tj < 4; ++tj)
                    acc[ti][tj] = __builtin_amdgcn_mfma_f32_16x16x32_fp8_fp8(
                        aF[ti], bF[tj], acc[ti][tj], 0, 0, 0);
        }
    }

    // ---- epilogue: K = c2[ga][gb] * exp(dist * t[ga][gb]) ----
    float zzv[4];
    int   gbv[4];
    #pragma unroll
    for (int tj = 0; tj < 4; ++tj) {
        int j = bcol + wc * 64 + tj * 16 + m;   // lane's column (C/D: col=lane&15)
        zzv[tj] = zz[j];
        gbv[tj] = gZ[j];
    }
    #pragma unroll
    for (int ti = 0; ti < 4; ++ti) {
        #pragma unroll
        for (int rg = 0; rg < 4; ++rg) {
            int i = brow + wr * 64 + ti * 16 + q * 4 + rg;  // C/D: row=quad*4+reg
            float xxi = xx[i];
            int   ga  = gX[i] * GRP;
            float* orow = out + (size_t)i * MCOLS + bcol + wc * 64 + m;
            #pragma unroll
            for (int tj = 0; tj < 4; ++tj) {
                float dot  = acc[ti][tj][rg];
                float dist = xxi + zzv[tj] - 2.0f * dot;
                float2 tc  = tab[ga + gbv[tj]];
                orow[tj * 16] = tc.y * __expf(dist * tc.x);
            }
        }
    }
}

// ---------------------------------------------------------------------------
extern "C" void kernel_launch(void* const* d_in, const int* in_sizes, int n_in,
                              void* d_out, int out_size, void* d_ws, size_t ws_size,
                              hipStream_t stream) {
    const float* X     = (const float*)d_in[0];
    const float* Z     = (const float*)d_in[1];
    const int*   gX    = (const int*)d_in[2];
    const int*   gZ    = (const int*)d_in[3];
    const float* emb   = (const float*)d_in[4];
    const float* sigma = (const float*)d_in[5];
    const float* ls    = (const float*)d_in[6];
    const float* gdp   = (const float*)d_in[7];

    char* ws = (char*)d_ws;
    const size_t XA_OFF  = 0;                              // 8192*512 = 4 MiB
    const size_t ZA_OFF  = XA_OFF + (size_t)NROWS * DDIM;  // 4 MiB
    const size_t XX_OFF  = ZA_OFF + (size_t)MCOLS * DDIM;
    const size_t ZZ_OFF  = XX_OFF + (size_t)NROWS * 4;
    const size_t TAB_OFF = ZZ_OFF + (size_t)MCOLS * 4;

    uint8_t* Xa  = (uint8_t*)(ws + XA_OFF);
    uint8_t* Za  = (uint8_t*)(ws + ZA_OFF);
    float* xx    = (float*)(ws + XX_OFF);
    float* zz    = (float*)(ws + ZZ_OFF);
    float2* tab  = (float2*)(ws + TAB_OFF);

    prep_all<<<2 * NROWS + 1, 256, 0, stream>>>(X, Z, (uint16_t*)Xa, (uint16_t*)Za,
                                                xx, zz, emb, sigma, ls, gdp, tab);
    mggp_gemm<<<4096, 256, 0, stream>>>(Xa, Za, xx, zz, gX, gZ, tab, (float*)d_out);
}